// Round 1
// baseline (19.809 us; speedup 1.0000x reference)
//
#include <hip/hip_runtime.h>
#include <math.h>

// NoncommutativeKATRepresentation: out[b,q] = T_q(xmean_b) * inner_sum[b,q]/IN
//   inner_sum[b,q] = sum_p c[q]*sin(pi*(q+1)*x[b,p])*W[q,p]
//   xmean_b = (1/D) sum_q tanh(inner_sum[b,q])
//   T_q(x) = cos(q*acos(x))  (valid: |xmean| < 1 strictly since it's a mean of tanh)
// theta input is dead (corr = 0.0*grad_sum == 0).

#define IN_DIM 100
#define MAXD   100
#define ROWS   8            // batch rows per block (1 wave each)
#define BLK    (ROWS * 64)

__global__ __launch_bounds__(BLK) void kat_kernel(
    const float* __restrict__ x, const float* __restrict__ W,
    const int* __restrict__ dimp, float* __restrict__ out, int B)
{
    const int D = *dimp;                 // 100 in practice, D <= MAXD
    const int P = (IN_DIM < D) ? IN_DIM : D;

    __shared__ float cq[MAXD];
    __shared__ float cw[MAXD][MAXD + 1]; // pad -> stride 101: column reads are 2 lanes/bank (free)
    __shared__ float xr[ROWS][IN_DIM];

    const int t = threadIdx.x;

    // per-q constant: coeff[q] * exp(-DELTA*k*k)
    if (t < MAXD) {
        float q = (float)t;
        float k = q + 1.0f;
        float coeff;
        if (t < 15) {
            coeff = 1.0f / k;
        } else {
            float S = 1.0f + 0.2f * logf(q / 15.0f) * (1.0f - expf(-0.03f * (q - 15.0f)));
            coeff = 1.0f / (k * S);
        }
        cq[t] = (t < D) ? coeff * expf(-0.03f * k * k) : 0.0f;
    }
    __syncthreads();

    // stage c[q]*W[q,p] into LDS (shared by all ROWS rows in this block)
    for (int i = t; i < MAXD * IN_DIM; i += BLK) {
        int q = i / IN_DIM, p = i - q * IN_DIM;
        float w = (q < D && p < P) ? W[q * MAXD + p] : 0.0f;
        cw[q][p] = cq[q] * w;
    }
    // stage x rows
    const int row0 = blockIdx.x * ROWS;
    for (int i = t; i < ROWS * IN_DIM; i += BLK) {
        int r = i / IN_DIM, p = i - r * IN_DIM;
        int b = row0 + r;
        xr[r][p] = (b < B) ? x[b * IN_DIM + p] : 0.0f;
    }
    __syncthreads();

    const int w    = t >> 6;       // wave id -> row within block
    const int lane = t & 63;
    const int b    = row0 + w;

    const int q0 = lane;
    const int q1 = lane + 64;
    const bool has1 = (q1 < D);

    const float pk0 = 3.14159265358979f * (float)(q0 + 1);
    const float pk1 = 3.14159265358979f * (float)(q1 + 1);

    float acc0 = 0.0f, acc1 = 0.0f;
    #pragma unroll 4
    for (int p = 0; p < P; ++p) {
        float xp = xr[w][p];                       // wave-uniform broadcast
        acc0 = fmaf(__sinf(pk0 * xp), cw[q0][p], acc0);
        if (has1)
            acc1 = fmaf(__sinf(pk1 * xp), cw[q1][p], acc1);
    }

    // xmean = (1/D) * sum_q tanh(inner_sum[q]);  rows with q>=D have cw==0 -> tanh(0)=0
    float s = ((q0 < D) ? tanhf(acc0) : 0.0f) + (has1 ? tanhf(acc1) : 0.0f);
    #pragma unroll
    for (int m = 32; m; m >>= 1) s += __shfl_xor(s, m);
    const float xm = s / (float)D;

    const float th  = acosf(xm);
    const float inv = 1.0f / (float)IN_DIM;
    if (b < B) {
        if (q0 < D) out[b * D + q0] = cosf((float)q0 * th) * acc0 * inv;
        if (has1)   out[b * D + q1] = cosf((float)q1 * th) * acc1 * inv;
    }
}

extern "C" void kernel_launch(void* const* d_in, const int* in_sizes, int n_in,
                              void* d_out, int out_size, void* d_ws, size_t ws_size,
                              hipStream_t stream) {
    const float* x    = (const float*)d_in[0];
    const float* W    = (const float*)d_in[1];
    // d_in[2] = theta (unused: corr == 0)
    const int*   dimp = (const int*)d_in[3];
    float*       out  = (float*)d_out;

    const int B = in_sizes[0] / IN_DIM;          // 4096
    const int grid = (B + ROWS - 1) / ROWS;      // 512 blocks of 512 threads

    hipLaunchKernelGGL(kat_kernel, dim3(grid), dim3(BLK), 0, stream,
                       x, W, dimp, out, B);
}

// Round 2
// 15.728 us; speedup vs baseline: 1.2595x; 1.2595x over previous
//
#include <hip/hip_runtime.h>
#include <math.h>

// out[b,q] = T_q(xmean_b) * inner_sum[b,q]/IN
//   inner_sum[b,q] = sum_p c[q]*sin(pi*(q+1)*x[b,p])*W[q,p]
//   xmean_b = (1/D) sum_q tanh(inner_sum[b,q]);  T_q(x)=cos(q*acos(x)), |xmean|<1
// theta input dead (corr == 0). sin in REVOLUTIONS: sin(pi*k*x) = v_sin((k/2)*x).

#define IN_DIM 100
#define MAXD   100
#define ROWS   8
#define BLK    (ROWS * 64)
#define INV2PI 0.15915494309189535f

__device__ __forceinline__ float fast_tanh(float v) {
    // tanh(v) = 1 - 2/(exp(2v)+1); overflow-safe (e=inf -> 1, e=0 -> -1)
    float e = __expf(2.0f * v);
    return 1.0f - 2.0f / (e + 1.0f);
}

__global__ __launch_bounds__(BLK) void kat_kernel(
    const float* __restrict__ x, const float* __restrict__ W,
    const int* __restrict__ dimp, float* __restrict__ out, int B)
{
    const int D = *dimp;
    const int P = (IN_DIM < D) ? IN_DIM : D;

    __shared__ float cq[MAXD];
    __shared__ float cw[MAXD][MAXD + 1];   // stride 101 -> 2-way (free) on column reads
    __shared__ float xr[ROWS][IN_DIM];

    const int t = threadIdx.x;

    // per-q constant: coeff[q] * exp(-DELTA*k*k), zero for q >= D
    if (t < MAXD) {
        float q = (float)t;
        float k = q + 1.0f;
        float coeff;
        if (t < 15) {
            coeff = 1.0f / k;
        } else {
            float S = 1.0f + 0.2f * __logf(q / 15.0f) * (1.0f - __expf(-0.03f * (q - 15.0f)));
            coeff = 1.0f / (k * S);
        }
        cq[t] = (t < D) ? coeff * __expf(-0.03f * k * k) : 0.0f;
    }
    const int row0 = blockIdx.x * ROWS;
    // stage x rows as float4 (row0*IN_DIM floats = 3200B*blockIdx -> 16B aligned)
    {
        const float4* x4 = (const float4*)(x + (size_t)row0 * IN_DIM);
        for (int i = t; i < ROWS * IN_DIM / 4; i += BLK) {
            int r = i / (IN_DIM / 4);
            int p = (i - r * (IN_DIM / 4)) * 4;
            float4 v;
            if (row0 + r < B) v = x4[i];
            else v = make_float4(0.f, 0.f, 0.f, 0.f);
            xr[r][p] = v.x; xr[r][p+1] = v.y; xr[r][p+2] = v.z; xr[r][p+3] = v.w;
        }
    }
    __syncthreads();   // cq ready
    // stage cw = cq[q]*W[q][p] via float4 global loads (W rows = 25 aligned float4)
    {
        const float4* W4 = (const float4*)W;
        for (int i = t; i < MAXD * IN_DIM / 4; i += BLK) {
            float4 wv = W4[i];
            int q = i / (IN_DIM / 4);
            int p = (i - q * (IN_DIM / 4)) * 4;
            float c = cq[q];  // 0 for q >= D
            cw[q][p]   = (p     < P) ? c * wv.x : 0.0f;
            cw[q][p+1] = (p + 1 < P) ? c * wv.y : 0.0f;
            cw[q][p+2] = (p + 2 < P) ? c * wv.z : 0.0f;
            cw[q][p+3] = (p + 3 < P) ? c * wv.w : 0.0f;
        }
    }
    __syncthreads();

    const int w    = t >> 6;
    const int lane = t & 63;
    const int b    = row0 + w;

    const int q0 = lane;
    const int q1 = lane + 64;
    const bool has1 = (q1 < D);
    const int q1c = (q1 < MAXD) ? q1 : (MAXD - 1);   // clamp row; garbage zeroed below
    const float m1 = has1 ? 1.0f : 0.0f;

    // revolutions factor: sin(pi*k*x) = sin2pi((k/2)*x)
    const float f0 = 0.5f * (float)(q0 + 1);
    const float f1 = 0.5f * (float)(q1 + 1);

    const float* __restrict__ row_a = &cw[q0][0];
    const float* __restrict__ row_b = &cw[q1c][0];
    const float* __restrict__ xw    = &xr[w][0];

    float acc0 = 0.0f, acc1 = 0.0f;
    if (D == MAXD) {
        #pragma unroll 4
        for (int p = 0; p < IN_DIM; ++p) {
            float xp = xw[p];
            acc0 = fmaf(__builtin_amdgcn_sinf(f0 * xp), row_a[p], acc0);
            acc1 = fmaf(__builtin_amdgcn_sinf(f1 * xp), row_b[p], acc1);
        }
    } else {
        #pragma unroll 4
        for (int p = 0; p < P; ++p) {
            float xp = xw[p];
            acc0 = fmaf(__builtin_amdgcn_sinf(f0 * xp), row_a[p], acc0);
            acc1 = fmaf(__builtin_amdgcn_sinf(f1 * xp), row_b[p], acc1);
        }
    }
    acc1 *= m1;                      // kill clamped-row garbage (q1 >= D)

    // xmean = (1/D) * sum_q tanh(acc); q>=D rows have acc==0 -> tanh 0
    float s = ((q0 < D) ? fast_tanh(acc0) : 0.0f) + fast_tanh(acc1);
    #pragma unroll
    for (int m = 32; m; m >>= 1) s += __shfl_xor(s, m);
    const float xm = s / (float)D;

    const float thr = acosf(xm) * INV2PI;   // theta in revolutions
    const float inv = 1.0f / (float)IN_DIM;
    if (b < B) {
        if (q0 < D) out[b * D + q0] = __builtin_amdgcn_cosf((float)q0 * thr) * acc0 * inv;
        if (has1)   out[b * D + q1] = __builtin_amdgcn_cosf((float)q1 * thr) * acc1 * inv;
    }
}

extern "C" void kernel_launch(void* const* d_in, const int* in_sizes, int n_in,
                              void* d_out, int out_size, void* d_ws, size_t ws_size,
                              hipStream_t stream) {
    const float* x    = (const float*)d_in[0];
    const float* W    = (const float*)d_in[1];
    // d_in[2] = theta (unused: corr == 0)
    const int*   dimp = (const int*)d_in[3];
    float*       out  = (float*)d_out;

    const int B = in_sizes[0] / IN_DIM;          // 4096
    const int grid = (B + ROWS - 1) / ROWS;      // 512 blocks x 512 threads

    hipLaunchKernelGGL(kat_kernel, dim3(grid), dim3(BLK), 0, stream,
                       x, W, dimp, out, B);
}

// Round 3
// 14.944 us; speedup vs baseline: 1.3256x; 1.0525x over previous
//
#include <hip/hip_runtime.h>
#include <math.h>

// out[b,q] = T_q(xmean_b) * inner_sum[b,q]/IN
//   inner_sum[b,q] = sum_p c[q]*sin(pi*(q+1)*x[b,p])*W[q,p]
//   xmean_b = (1/D) sum_q tanh(inner_sum[b,q]);  T_q(x)=cos(q*acos(x)), |xmean|<1
// theta input dead (corr == 0). sin in REVOLUTIONS: sin(pi*k*x) = v_sin((k/2)*x).

#define IN_DIM 100
#define MAXD   100
#define ROWS   16
#define BLK    (ROWS * 64)      // 1024 threads, 16 waves
#define INV2PI 0.15915494309189535f

__device__ __forceinline__ float fast_tanh(float v) {
    float e = __expf(2.0f * v);
    return 1.0f - 2.0f / (e + 1.0f);
}

__global__ __launch_bounds__(BLK, 4) void kat_kernel(
    const float* __restrict__ x, const float* __restrict__ W,
    const int* __restrict__ dimp, float* __restrict__ out, int B)
{
    const int D = *dimp;
    const int P = (IN_DIM < D) ? IN_DIM : D;

    __shared__ float cq[MAXD];
    __shared__ float cw[MAXD][MAXD + 1];   // stride 101: column reads conflict-free
    __shared__ float xr[ROWS][IN_DIM];     // row stride 400B -> float4-aligned

    const int t = threadIdx.x;

    if (t < MAXD) {
        float q = (float)t;
        float k = q + 1.0f;
        float coeff;
        if (t < 15) {
            coeff = 1.0f / k;
        } else {
            float S = 1.0f + 0.2f * __logf(q / 15.0f) * (1.0f - __expf(-0.03f * (q - 15.0f)));
            coeff = 1.0f / (k * S);
        }
        cq[t] = (t < D) ? coeff * __expf(-0.03f * k * k) : 0.0f;
    }
    const int row0 = blockIdx.x * ROWS;
    {   // stage x rows (float4; row0*IN_DIM*4 bytes is 16B-aligned)
        const float4* x4 = (const float4*)(x + (size_t)row0 * IN_DIM);
        for (int i = t; i < ROWS * IN_DIM / 4; i += BLK) {
            int r = i / (IN_DIM / 4);
            int p = (i - r * (IN_DIM / 4)) * 4;
            float4 v;
            if (row0 + r < B) v = x4[i];
            else v = make_float4(0.f, 0.f, 0.f, 0.f);
            xr[r][p] = v.x; xr[r][p+1] = v.y; xr[r][p+2] = v.z; xr[r][p+3] = v.w;
        }
    }
    __syncthreads();   // cq ready
    {   // stage cw = cq[q]*W[q][p]
        const float4* W4 = (const float4*)W;
        for (int i = t; i < MAXD * IN_DIM / 4; i += BLK) {
            float4 wv = W4[i];
            int q = i / (IN_DIM / 4);
            int p = (i - q * (IN_DIM / 4)) * 4;
            float c = cq[q];  // 0 for q >= D
            cw[q][p]   = (p     < P) ? c * wv.x : 0.0f;
            cw[q][p+1] = (p + 1 < P) ? c * wv.y : 0.0f;
            cw[q][p+2] = (p + 2 < P) ? c * wv.z : 0.0f;
            cw[q][p+3] = (p + 3 < P) ? c * wv.w : 0.0f;
        }
    }
    __syncthreads();

    const int w    = t >> 6;
    const int lane = t & 63;
    const int b    = row0 + w;

    const int q0 = lane;
    const int q1 = lane + 64;
    const bool has1 = (q1 < D);
    const int q1c = (q1 < MAXD) ? q1 : (MAXD - 1);
    const float m1 = has1 ? 1.0f : 0.0f;

    const float f0 = 0.5f * (float)(q0 + 1);   // revolutions: sin(pi*k*x)=sin2pi((k/2)x)
    const float f1 = 0.5f * (float)(q1 + 1);

    const float* __restrict__ row_a = &cw[q0][0];
    const float* __restrict__ row_b = &cw[q1c][0];
    const float4* __restrict__ xw4  = (const float4*)&xr[w][0];

    float acc0 = 0.0f, acc1 = 0.0f;
    if (D == MAXD) {
        // deep pipeline: 10 iters/body -> ~25 independent LDS reads per region
        #pragma unroll 10
        for (int p4 = 0; p4 < IN_DIM / 4; ++p4) {
            float4 xv = xw4[p4];                     // b128 broadcast
            const int p = p4 * 4;
            float xp;
            xp = xv.x;
            acc0 = fmaf(__builtin_amdgcn_sinf(f0 * xp), row_a[p],     acc0);
            acc1 = fmaf(__builtin_amdgcn_sinf(f1 * xp), row_b[p],     acc1);
            xp = xv.y;
            acc0 = fmaf(__builtin_amdgcn_sinf(f0 * xp), row_a[p + 1], acc0);
            acc1 = fmaf(__builtin_amdgcn_sinf(f1 * xp), row_b[p + 1], acc1);
            xp = xv.z;
            acc0 = fmaf(__builtin_amdgcn_sinf(f0 * xp), row_a[p + 2], acc0);
            acc1 = fmaf(__builtin_amdgcn_sinf(f1 * xp), row_b[p + 2], acc1);
            xp = xv.w;
            acc0 = fmaf(__builtin_amdgcn_sinf(f0 * xp), row_a[p + 3], acc0);
            acc1 = fmaf(__builtin_amdgcn_sinf(f1 * xp), row_b[p + 3], acc1);
        }
    } else {
        #pragma unroll 4
        for (int p = 0; p < P; ++p) {
            float xp = xr[w][p];
            acc0 = fmaf(__builtin_amdgcn_sinf(f0 * xp), row_a[p], acc0);
            acc1 = fmaf(__builtin_amdgcn_sinf(f1 * xp), row_b[p], acc1);
        }
    }
    acc1 *= m1;

    float s = ((q0 < D) ? fast_tanh(acc0) : 0.0f) + fast_tanh(acc1);
    #pragma unroll
    for (int m = 32; m; m >>= 1) s += __shfl_xor(s, m);
    const float xm = s / (float)D;

    const float thr = acosf(xm) * INV2PI;
    const float inv = 1.0f / (float)IN_DIM;
    if (b < B) {
        if (q0 < D) out[b * D + q0] = __builtin_amdgcn_cosf((float)q0 * thr) * acc0 * inv;
        if (has1)   out[b * D + q1] = __builtin_amdgcn_cosf((float)q1 * thr) * acc1 * inv;
    }
}

extern "C" void kernel_launch(void* const* d_in, const int* in_sizes, int n_in,
                              void* d_out, int out_size, void* d_ws, size_t ws_size,
                              hipStream_t stream) {
    const float* x    = (const float*)d_in[0];
    const float* W    = (const float*)d_in[1];
    // d_in[2] = theta (unused: corr == 0)
    const int*   dimp = (const int*)d_in[3];
    float*       out  = (float*)d_out;

    const int B = in_sizes[0] / IN_DIM;          // 4096
    const int grid = (B + ROWS - 1) / ROWS;      // 256 blocks x 1024 threads

    hipLaunchKernelGGL(kat_kernel, dim3(grid), dim3(BLK), 0, stream,
                       x, W, dimp, out, B);
}